// Round 4
// baseline (244.532 us; speedup 1.0000x reference)
//
#include <hip/hip_runtime.h>
#include <hip/hip_bf16.h>

// XDeepFM CIN, fused 2-layer MFMA kernel for gfx950 — v4: barrier-free K-loops.
// A-fragments are generated IN REGISTERS from V (f32, LDS) / H (bf16, LDS):
// no Z staging, no __syncthreads in either K-loop (V/H read-only there).
// Layer 0: K = 40i x 48j = 1920 (60 slices of 32).  Layer 1: K = 39i x 64j = 2496 (78 slices).
// B (packed bf16 W) prefetched one slice ahead from L2; MFMA 16x16x32 bf16, 2x2 waves,
// wave tile 64x64, per-lane 4x4 f32x4 accumulators.

using short8 = __attribute__((ext_vector_type(8))) short;
using f32x4  = __attribute__((ext_vector_type(4))) float;

#define VSTR 52                       // f32 per V row (208B pitch; 52w%32=20 -> b128 conflict-free)
#define V_BYTES (128 * VSTR * 4)      // 26624
#define HSTR 72                       // bf16 per H row (144B pitch; 36w%32=4 -> b128 conflict-free)
#define H_BYTES (128 * HSTR * 2)      // 18432
#define SMEM_BYTES (V_BYTES + H_BYTES)  // 45056 -> 3 blocks/CU

#define NS0 60                        // layer-0 K slices (1920/32)
#define NS1 78                        // layer-1 K slices (2496/32)
#define NFRAG ((NS0 + NS1) * 8 * 64)  // packed-B fragments

__device__ __forceinline__ unsigned short f2bf(float x) {
  __hip_bfloat16 h = __float2bfloat16(x);
  return __builtin_bit_cast(unsigned short, h);
}
// packed f32x2 -> bf16x2 (dst.lo = bf16(lo), dst.hi = bf16(hi))
__device__ __forceinline__ unsigned cvt2(float lo, float hi) {
  unsigned r;
  asm("v_cvt_pk_bf16_f32 %0, %1, %2" : "=v"(r) : "v"(lo), "v"(hi));
  return r;
}
__device__ __forceinline__ float bf_lo(unsigned w) {
  return __builtin_bit_cast(float, w << 16);
}
__device__ __forceinline__ float bf_hi(unsigned w) {
  return __builtin_bit_cast(float, w & 0xffff0000u);
}

// ---------------- W pre-pack (unchanged, verified): one B-fragment per thread ----------------
// Fragment order: slice s, n-block nb, lane l holds W[k=32s+(l>>4)*8+ii][n=nb*16+(l&15)].
__global__ void pack_w(const float* __restrict__ W0, const float* __restrict__ W1,
                       short8* __restrict__ wpk) {
  int fid = blockIdx.x * 256 + threadIdx.x;
  if (fid >= NFRAG) return;
  int lane = fid & 63;
  int t2 = fid >> 6;
  int nb = t2 & 7, s = t2 >> 3;
  int n = nb * 16 + (lane & 15);
  int klb = (lane >> 4) * 8;
  short8 frag;
  #pragma unroll
  for (int ii = 0; ii < 8; ii++) {
    float val;
    if (s < NS0) {                     // layer 0: k = i*48 + j
      int k = s * 32 + klb + ii;
      int i = k / 48, j = k - i * 48;
      val = (i < 39 && j < 39) ? W0[(i * 39 + j) * 128 + n] : 0.f;
    } else {                           // layer 1: k = i*64 + j, exact
      int k = (s - NS0) * 32 + klb + ii;
      int i = k >> 6, j = k & 63;
      val = W1[(i * 64 + j) * 128 + n];
    }
    frag[ii] = (short)f2bf(val);
  }
  wpk[fid] = frag;
}

// ---------------- fused CIN main kernel ----------------
__global__ __launch_bounds__(256, 3) void cin_main(const float* __restrict__ X,
                                                   const short8* __restrict__ wpk,
                                                   float* __restrict__ out) {
  extern __shared__ char smem[];
  float* V          = (float*)smem;                      // [128][52] f32
  unsigned short* H = (unsigned short*)(smem + V_BYTES); // [128][72] bf16

  const int t    = threadIdx.x;
  const int lane = t & 63;
  const int w    = t >> 6;
  const int wm   = w >> 1, wn = w & 1;     // 2x2 wave grid; wave tile 64 rows x 64 cols
  const int l15  = lane & 15, l4 = lane >> 4;
  const int b0   = blockIdx.x * 8;

  // ---- stage x tile: x[b0+bl, i, d] -> V[bl*16+d][i]; cols 39..51 zeroed ----
  const float* xb = X + (size_t)b0 * 624;   // 8*39*16 floats
  for (int f = t * 4; f < 4992; f += 1024) {
    float4 v4 = *(const float4*)(xb + f);
    int bl = f / 624;
    int rem = f - bl * 624;
    int i = rem >> 4, d0 = rem & 15;
    int r = bl * 16 + d0;
    V[(r + 0) * VSTR + i] = v4.x;
    V[(r + 1) * VSTR + i] = v4.y;
    V[(r + 2) * VSTR + i] = v4.z;
    V[(r + 3) * VSTR + i] = v4.w;
  }
  if (t < 128) {
    #pragma unroll
    for (int c = 39; c < VSTR; c++) V[t * VSTR + c] = 0.f;
  }
  __syncthreads();   // barrier #1 (V ready) — no more barriers until layer handoff

  // per-mi row base pointers (rows this lane's A-fragments come from)
  const float* vrow[4];
  const unsigned short* hrow[4];
  #pragma unroll
  for (int mi = 0; mi < 4; mi++) {
    int row = wm * 64 + mi * 16 + l15;
    vrow[mi] = V + row * VSTR;
    hrow[mi] = H + row * HSTR;
  }
  const short8* wb = wpk + wn * 256 + lane;   // + s*512 + ni*64

  f32x4 acc[4][4];
  #pragma unroll
  for (int mi = 0; mi < 4; mi++)
    #pragma unroll
    for (int ni = 0; ni < 4; ni++)
      acc[mi][ni] = (f32x4){0.f, 0.f, 0.f, 0.f};

  short8 bn[4], bc[4];
  #pragma unroll
  for (int ni = 0; ni < 4; ni++) bn[ni] = wb[ni * 64];   // prefetch slice 0

  // ================= layer 0: 60 slices, NO barriers =================
  #pragma unroll 1
  for (int ss = 0; ss < NS0; ss++) {
    #pragma unroll
    for (int ni = 0; ni < 4; ni++) {
      bc[ni] = bn[ni];
      bn[ni] = wb[(ss + 1) * 512 + ni * 64];  // ss=59 prefetches layer-1 slice 0 — wanted!
    }
    // chunk k = 32*ss + 8*l4 -> i = k/48, j0 = k%48 (exact magic div by 6 on c=k/8)
    int c  = 4 * ss + l4;
    int i  = (c * 43691) >> 18;
    int j0 = (c - i * 6) * 8;
    short8 a[4];
    #pragma unroll
    for (int mi = 0; mi < 4; mi++) {
      float vi  = vrow[mi][i];
      float4 lo = *(const float4*)(vrow[mi] + j0);
      float4 hi = *(const float4*)(vrow[mi] + j0 + 4);
      uint4 pk;
      pk.x = cvt2(vi * lo.x, vi * lo.y);
      pk.y = cvt2(vi * lo.z, vi * lo.w);
      pk.z = cvt2(vi * hi.x, vi * hi.y);
      pk.w = cvt2(vi * hi.z, vi * hi.w);
      a[mi] = __builtin_bit_cast(short8, pk);
    }
    #pragma unroll
    for (int ni = 0; ni < 4; ni++)
      #pragma unroll
      for (int mi = 0; mi < 4; mi++)
        acc[mi][ni] = __builtin_amdgcn_mfma_f32_16x16x32_bf16(a[mi], bc[ni], acc[mi][ni], 0, 0, 0);
  }

  // ---- layer-0 epilogue: relu; cols 0..63 -> H; cols 64..127 -> out[b, 0:64] ----
  if (wn == 0) {
    #pragma unroll
    for (int mi = 0; mi < 4; mi++)
      #pragma unroll
      for (int ni = 0; ni < 4; ni++)
        #pragma unroll
        for (int e = 0; e < 4; e++) {
          int row = wm * 64 + mi * 16 + l4 * 4 + e;
          int col = ni * 16 + l15;
          H[row * HSTR + col] = f2bf(fmaxf(acc[mi][ni][e], 0.f));
        }
  } else {
    #pragma unroll
    for (int mi = 0; mi < 4; mi++)
      #pragma unroll
      for (int ni = 0; ni < 4; ni++) {
        float s = fmaxf(acc[mi][ni][0], 0.f) + fmaxf(acc[mi][ni][1], 0.f)
                + fmaxf(acc[mi][ni][2], 0.f) + fmaxf(acc[mi][ni][3], 0.f);
        s += __shfl_xor(s, 16);
        s += __shfl_xor(s, 32);
        if (lane < 16)
          out[(size_t)(b0 + wm * 4 + mi) * 192 + ni * 16 + lane] = s;
      }
  }

  // reset accumulators for layer 1
  #pragma unroll
  for (int mi = 0; mi < 4; mi++)
    #pragma unroll
    for (int ni = 0; ni < 4; ni++)
      acc[mi][ni] = (f32x4){0.f, 0.f, 0.f, 0.f};

  __syncthreads();   // barrier #2 (H ready)

  // ================= layer 1: 78 slices, NO barriers =================
  #pragma unroll 1
  for (int ss = 0; ss < NS1; ss++) {
    #pragma unroll
    for (int ni = 0; ni < 4; ni++) {
      bc[ni] = bn[ni];
      if (ss + 1 < NS1) bn[ni] = wb[(NS0 + ss + 1) * 512 + ni * 64];
    }
    int i  = ss >> 1;                       // k = i*64 + j; chunk j0 = (ss&1)*32 + l4*8
    int j0 = ((ss & 1) << 5) + (l4 << 3);
    short8 a[4];
    #pragma unroll
    for (int mi = 0; mi < 4; mi++) {
      float vi = vrow[mi][i];
      uint4 hw = *(const uint4*)(hrow[mi] + j0);
      uint4 pk;
      pk.x = cvt2(vi * bf_lo(hw.x), vi * bf_hi(hw.x));
      pk.y = cvt2(vi * bf_lo(hw.y), vi * bf_hi(hw.y));
      pk.z = cvt2(vi * bf_lo(hw.z), vi * bf_hi(hw.z));
      pk.w = cvt2(vi * bf_lo(hw.w), vi * bf_hi(hw.w));
      a[mi] = __builtin_bit_cast(short8, pk);
    }
    #pragma unroll
    for (int ni = 0; ni < 4; ni++)
      #pragma unroll
      for (int mi = 0; mi < 4; mi++)
        acc[mi][ni] = __builtin_amdgcn_mfma_f32_16x16x32_bf16(a[mi], bc[ni], acc[mi][ni], 0, 0, 0);
  }

  // ---- layer-1 epilogue: relu, reduce over d, out[b, 64:192] ----
  #pragma unroll
  for (int mi = 0; mi < 4; mi++)
    #pragma unroll
    for (int ni = 0; ni < 4; ni++) {
      float s = fmaxf(acc[mi][ni][0], 0.f) + fmaxf(acc[mi][ni][1], 0.f)
              + fmaxf(acc[mi][ni][2], 0.f) + fmaxf(acc[mi][ni][3], 0.f);
      s += __shfl_xor(s, 16);
      s += __shfl_xor(s, 32);
      if (lane < 16)
        out[(size_t)(b0 + wm * 4 + mi) * 192 + 64 + wn * 64 + ni * 16 + lane] = s;
    }
}

extern "C" void kernel_launch(void* const* d_in, const int* in_sizes, int n_in,
                              void* d_out, int out_size, void* d_ws, size_t ws_size,
                              hipStream_t stream) {
  (void)in_sizes; (void)n_in; (void)out_size; (void)ws_size;
  const float* X  = (const float*)d_in[0];   // [8192,39,16]
  const float* W0 = (const float*)d_in[1];   // [1521,128]
  const float* W1 = (const float*)d_in[2];   // [2496,128]
  float* out = (float*)d_out;                // [8192,192]
  short8* wpk = (short8*)d_ws;               // packed bf16 W0|W1, 1.13 MB

  pack_w<<<(NFRAG + 255) / 256, 256, 0, stream>>>(W0, W1, wpk);
  cin_main<<<1024, 256, SMEM_BYTES, stream>>>(X, wpk, out);
}

// Round 5
// 231.071 us; speedup vs baseline: 1.0583x; 1.0583x over previous
//
#include <hip/hip_runtime.h>
#include <hip/hip_bf16.h>

// XDeepFM CIN fused 2-layer MFMA kernel, gfx950 — v5.
// 32x32x16 bf16 MFMA; 4 waves x 32 rows (no A-gen duplication); i-major K-loops
// (vi scalar-hoisted, j0 immediate); barrier-free K-loops; B prefetched 1 slice.
// Layer 0: K = 40i x 48j = 1920 (120 K16-slices). Layer 1: K = 39i x 64j = 2496 (156 slices).

using short8 = __attribute__((ext_vector_type(8))) short;
using f32x16 = __attribute__((ext_vector_type(16))) float;

#define VSTR 52                         // f32 per V row (208B pitch; conflict-free b128)
#define V_BYTES (128 * VSTR * 4)        // 26624
#define HSTR 72                         // bf16 per H row (144B pitch; conflict-free b128)
#define H_BYTES (128 * HSTR * 2)        // 18432
#define SMEM_BYTES (V_BYTES + H_BYTES)  // 45056 -> 3 blocks/CU

#define NSL0 120                        // layer-0 K=16 slices
#define NSL1 156                        // layer-1 K=16 slices
#define NSL  (NSL0 + NSL1)              // 276
#define NFRAG (NSL * 4 * 64)            // 70656 16B fragments = 1.13 MB

__device__ __forceinline__ unsigned short f2bf(float x) {
  __hip_bfloat16 h = __float2bfloat16(x);
  return __builtin_bit_cast(unsigned short, h);
}
__device__ __forceinline__ unsigned cvt2(float lo, float hi) {
  unsigned r;
  asm("v_cvt_pk_bf16_f32 %0, %1, %2" : "=v"(r) : "v"(lo), "v"(hi));
  return r;
}
__device__ __forceinline__ float bf_lo(unsigned w) {
  return __builtin_bit_cast(float, w << 16);
}
__device__ __forceinline__ float bf_hi(unsigned w) {
  return __builtin_bit_cast(float, w & 0xffff0000u);
}

// ---------------- W pre-pack: one 32x32x16 B-fragment per thread ----------------
// Fragment (slice s, n-block nb): lane l holds W[k = 16s + (l>>5)*8 + ii][n = nb*32 + (l&31)].
__global__ void pack_w(const float* __restrict__ W0, const float* __restrict__ W1,
                       short8* __restrict__ wpk) {
  int fid = blockIdx.x * 256 + threadIdx.x;
  if (fid >= NFRAG) return;
  int lane = fid & 63;
  int t2 = fid >> 6;
  int nb = t2 & 3, s = t2 >> 2;         // s in [0, 276)
  int n = nb * 32 + (lane & 31);
  int kb = (lane >> 5) * 8;
  short8 frag;
  #pragma unroll
  for (int ii = 0; ii < 8; ii++) {
    float val;
    if (s < NSL0) {                     // layer 0: k = i*48 + j
      int k = s * 16 + kb + ii;
      int i = k / 48, j = k - i * 48;
      val = (i < 39 && j < 39) ? W0[(i * 39 + j) * 128 + n] : 0.f;
    } else {                            // layer 1: k = i*64 + j, exact
      int k = (s - NSL0) * 16 + kb + ii;
      int i = k >> 6, j = k & 63;
      val = W1[(i * 64 + j) * 128 + n];
    }
    frag[ii] = (short)f2bf(val);
  }
  wpk[fid] = frag;
}

// ---------------- fused CIN main kernel ----------------
__global__ __launch_bounds__(256, 3) void cin_main(const float* __restrict__ X,
                                                   const short8* __restrict__ wpk,
                                                   float* __restrict__ out) {
  extern __shared__ char smem[];
  float* V          = (float*)smem;                      // [128][52] f32
  unsigned short* H = (unsigned short*)(smem + V_BYTES); // [128][72] bf16

  const int t    = threadIdx.x;
  const int lane = t & 63;
  const int w    = t >> 6;               // wave id: rows [w*32, w*32+32)
  const int l31  = lane & 31, hi = lane >> 5;
  const int b0   = blockIdx.x * 8;

  // ---- stage x tile: x[b0+bl, i, d] -> V[bl*16+d][i]; cols 39..51 zeroed ----
  const float* xb = X + (size_t)b0 * 624;   // 8*39*16 floats
  for (int f = t * 4; f < 4992; f += 1024) {
    float4 v4 = *(const float4*)(xb + f);
    int bl = f / 624;
    int rem = f - bl * 624;
    int i = rem >> 4, d0 = rem & 15;
    int r = bl * 16 + d0;
    V[(r + 0) * VSTR + i] = v4.x;
    V[(r + 1) * VSTR + i] = v4.y;
    V[(r + 2) * VSTR + i] = v4.z;
    V[(r + 3) * VSTR + i] = v4.w;
  }
  if (t < 128) {
    #pragma unroll
    for (int c = 39; c < VSTR; c++) V[t * VSTR + c] = 0.f;
  }
  __syncthreads();   // barrier #1: V ready

  const int row = w * 32 + l31;          // this lane's A row (32x32 A: row = lane&31)
  const float* vr          = V + row * VSTR;
  const unsigned short* hr = H + row * HSTR;

  f32x16 acc[4];
  #pragma unroll
  for (int nb = 0; nb < 4; nb++)
    #pragma unroll
    for (int e = 0; e < 16; e++) acc[nb][e] = 0.f;

  short8 bc[4], bn[4];
  #pragma unroll
  for (int nb = 0; nb < 4; nb++) bn[nb] = wpk[nb * 64 + lane];   // slice 0

  // ================= layer 0: 40 i-groups x 3 K16-slices, NO barriers =================
  #pragma unroll 1
  for (int i40 = 0; i40 < 40; i40++) {
    float vi = vr[i40];
    #pragma unroll
    for (int rr = 0; rr < 3; rr++) {
      int sg = i40 * 3 + rr;
      #pragma unroll
      for (int nb = 0; nb < 4; nb++) {
        bc[nb] = bn[nb];
        bn[nb] = wpk[(sg + 1) * 256 + nb * 64 + lane];   // sg=119 -> layer-1 slice 0: wanted
      }
      const float* jp = vr + 16 * rr + 8 * hi;           // j0 = 16rr + 8hi (pad j>=39 is 0)
      float4 lo = *(const float4*)jp;
      float4 h4 = *(const float4*)(jp + 4);
      uint4 pk;
      pk.x = cvt2(vi * lo.x, vi * lo.y);
      pk.y = cvt2(vi * lo.z, vi * lo.w);
      pk.z = cvt2(vi * h4.x, vi * h4.y);
      pk.w = cvt2(vi * h4.z, vi * h4.w);
      short8 a = __builtin_bit_cast(short8, pk);
      #pragma unroll
      for (int nb = 0; nb < 4; nb++)
        acc[nb] = __builtin_amdgcn_mfma_f32_32x32x16_bf16(a, bc[nb], acc[nb], 0, 0, 0);
    }
  }

  // ---- layer-0 epilogue ----
  // C/D layout (verified m74/m101): col = lane&31, rowtile = (r&3) + 8*(r>>2) + 4*hi.
  // cols 0..63 (nb 0,1) -> H; cols 64..127 (nb 2,3) -> sum over d -> out[b, 0:64].
  #pragma unroll
  for (int nb = 0; nb < 2; nb++)
    #pragma unroll
    for (int r = 0; r < 16; r++) {
      int rt = (r & 3) + 8 * (r >> 2) + 4 * hi;
      H[(w * 32 + rt) * HSTR + nb * 32 + l31] = f2bf(fmaxf(acc[nb][r], 0.f));
    }
  #pragma unroll
  for (int nb = 2; nb < 4; nb++) {
    float s0 = 0.f, s1 = 0.f;
    #pragma unroll
    for (int r = 0; r < 8; r++)  s0 += fmaxf(acc[nb][r], 0.f);   // rows < 16  -> b = b0+2w
    #pragma unroll
    for (int r = 8; r < 16; r++) s1 += fmaxf(acc[nb][r], 0.f);   // rows >= 16 -> b = b0+2w+1
    s0 += __shfl_xor(s0, 32);
    s1 += __shfl_xor(s1, 32);
    out[(size_t)(b0 + 2 * w + hi) * 192 + (nb - 2) * 32 + l31] = hi ? s1 : s0;
  }
  __syncthreads();   // barrier #2: H ready

  #pragma unroll
  for (int nb = 0; nb < 4; nb++)
    #pragma unroll
    for (int e = 0; e < 16; e++) acc[nb][e] = 0.f;

  // ================= layer 1: 39 i-groups x 4 K16-slices, NO barriers =================
  #pragma unroll 1
  for (int i39 = 0; i39 < 39; i39++) {
    float vi = vr[i39];
    #pragma unroll
    for (int rr = 0; rr < 4; rr++) {
      int sg = NSL0 + i39 * 4 + rr;
      #pragma unroll
      for (int nb = 0; nb < 4; nb++) {
        bc[nb] = bn[nb];
        if (sg + 1 < NSL) bn[nb] = wpk[(sg + 1) * 256 + nb * 64 + lane];
      }
      const unsigned short* jp = hr + 16 * rr + 8 * hi;  // j0 = 16rr + 8hi
      uint4 hw = *(const uint4*)jp;
      uint4 pk;
      pk.x = cvt2(vi * bf_lo(hw.x), vi * bf_hi(hw.x));
      pk.y = cvt2(vi * bf_lo(hw.y), vi * bf_hi(hw.y));
      pk.z = cvt2(vi * bf_lo(hw.z), vi * bf_hi(hw.z));
      pk.w = cvt2(vi * bf_lo(hw.w), vi * bf_hi(hw.w));
      short8 a = __builtin_bit_cast(short8, pk);
      #pragma unroll
      for (int nb = 0; nb < 4; nb++)
        acc[nb] = __builtin_amdgcn_mfma_f32_32x32x16_bf16(a, bc[nb], acc[nb], 0, 0, 0);
    }
  }

  // ---- layer-1 epilogue: relu, sum over d, out[b, 64:192] ----
  #pragma unroll
  for (int nb = 0; nb < 4; nb++) {
    float s0 = 0.f, s1 = 0.f;
    #pragma unroll
    for (int r = 0; r < 8; r++)  s0 += fmaxf(acc[nb][r], 0.f);
    #pragma unroll
    for (int r = 8; r < 16; r++) s1 += fmaxf(acc[nb][r], 0.f);
    s0 += __shfl_xor(s0, 32);
    s1 += __shfl_xor(s1, 32);
    out[(size_t)(b0 + 2 * w + hi) * 192 + 64 + nb * 32 + l31] = hi ? s1 : s0;
  }
}

extern "C" void kernel_launch(void* const* d_in, const int* in_sizes, int n_in,
                              void* d_out, int out_size, void* d_ws, size_t ws_size,
                              hipStream_t stream) {
  (void)in_sizes; (void)n_in; (void)out_size; (void)ws_size;
  const float* X  = (const float*)d_in[0];   // [8192,39,16]
  const float* W0 = (const float*)d_in[1];   // [1521,128]
  const float* W1 = (const float*)d_in[2];   // [2496,128]
  float* out = (float*)d_out;                // [8192,192]
  short8* wpk = (short8*)d_ws;               // packed bf16 W0|W1, 1.13 MB

  pack_w<<<(NFRAG + 255) / 256, 256, 0, stream>>>(W0, W1, wpk);
  cin_main<<<1024, 256, SMEM_BYTES, stream>>>(X, wpk, out);
}

// Round 6
// 188.364 us; speedup vs baseline: 1.2982x; 1.2267x over previous
//
#include <hip/hip_runtime.h>
#include <hip/hip_bf16.h>

// XDeepFM CIN fused 2-layer MFMA kernel, gfx950 — v6.
// 32x32x16 bf16 MFMA; 4 waves x 64 rows (256 rows = 16 b's per block, 512 blocks,
// exactly 2 blocks/CU). B slices staged in LDS via global_load_lds (4KB/slice,
// double-buffered, shared by all 4 waves -> B L2 traffic /8 vs v5). A-gen sources
// (vj/hj windows) register-cached packed; K-loops touch LDS only for conflict-free
// B reads. V stored bf16 (precision: one extra bf16 pre-round on v).
// Layer 0: K = 40i x 48j = 1920 (120 K16-slices). Layer 1: K = 39i x 64j = 2496 (156).

using short8 = __attribute__((ext_vector_type(8))) short;
using f32x16 = __attribute__((ext_vector_type(16))) float;

#define VS 56                           // bf16 per V row (112B pitch: 7 slots, gcd(7,8)=1)
#define V_BYTES (256 * VS * 2)          // 28672
#define HS 72                           // bf16 per H row (144B pitch: 9 slots, gcd(9,8)=1)
#define H_BYTES (256 * HS * 2)          // 36864
#define BB_OFF (V_BYTES + H_BYTES)      // 65536
#define SMEM_BYTES (BB_OFF + 8192)      // 73728 -> 2 blocks/CU

#define NSL0 120                        // layer-0 K16 slices
#define NSL1 156                        // layer-1 K16 slices
#define NSL  (NSL0 + NSL1)              // 276
#define NFRAG (NSL * 256)               // 70656 16B fragments = 1.13 MB

__device__ __forceinline__ unsigned short f2bf(float x) {
  __hip_bfloat16 h = __float2bfloat16(x);
  return __builtin_bit_cast(unsigned short, h);
}
__device__ __forceinline__ unsigned cvt2(float lo, float hi) {
  unsigned r;
  asm("v_cvt_pk_bf16_f32 %0, %1, %2" : "=v"(r) : "v"(lo), "v"(hi));
  return r;
}
__device__ __forceinline__ float bf_lo(unsigned w) {
  return __builtin_bit_cast(float, w << 16);
}
__device__ __forceinline__ float bf_hi(unsigned w) {
  return __builtin_bit_cast(float, w & 0xffff0000u);
}
__device__ __forceinline__ float bf2f(unsigned short b) {
  return __builtin_bit_cast(float, ((unsigned)b) << 16);
}
// A-fragment from scalar vi x packed-bf16x8 window
__device__ __forceinline__ short8 mk_a(float vi, uint4 p) {
  uint4 pk;
  pk.x = cvt2(vi * bf_lo(p.x), vi * bf_hi(p.x));
  pk.y = cvt2(vi * bf_lo(p.y), vi * bf_hi(p.y));
  pk.z = cvt2(vi * bf_lo(p.z), vi * bf_hi(p.z));
  pk.w = cvt2(vi * bf_lo(p.w), vi * bf_hi(p.w));
  return __builtin_bit_cast(short8, pk);
}
// async 16B/lane global -> LDS (wave-uniform LDS base, per-lane global src)
__device__ __forceinline__ void stage16(const void* g, char* l) {
  __builtin_amdgcn_global_load_lds((const __attribute__((address_space(1))) void*)g,
                                   (__attribute__((address_space(3))) void*)l, 16, 0, 0);
}

// ---------------- W pre-pack (verified v5 layout): one 32x32x16 B-fragment per thread ----
// Fragment (slice s, n-block nb): lane l holds W[k = 16s + (l>>5)*8 + ii][n = nb*32 + (l&31)].
__global__ void pack_w(const float* __restrict__ W0, const float* __restrict__ W1,
                       short8* __restrict__ wpk) {
  int fid = blockIdx.x * 256 + threadIdx.x;
  if (fid >= NFRAG) return;
  int lane = fid & 63;
  int t2 = fid >> 6;
  int nb = t2 & 3, s = t2 >> 2;
  int n = nb * 32 + (lane & 31);
  int kb = (lane >> 5) * 8;
  short8 frag;
  #pragma unroll
  for (int ii = 0; ii < 8; ii++) {
    float val;
    if (s < NSL0) {                     // layer 0: k = i*48 + j
      int k = s * 16 + kb + ii;
      int i = k / 48, j = k - i * 48;
      val = (i < 39 && j < 39) ? W0[(i * 39 + j) * 128 + n] : 0.f;
    } else {                            // layer 1: k = i*64 + j, exact
      int k = (s - NSL0) * 16 + kb + ii;
      int i = k >> 6, j = k & 63;
      val = W1[(i * 64 + j) * 128 + n];
    }
    frag[ii] = (short)f2bf(val);
  }
  wpk[fid] = frag;
}

// ---------------- fused CIN main kernel ----------------
__global__ __launch_bounds__(256, 2) void cin_main(const float* __restrict__ X,
                                                   const short8* __restrict__ wpk,
                                                   float* __restrict__ out) {
  extern __shared__ char smem[];
  unsigned short* Vb = (unsigned short*)smem;            // [256][56] bf16
  unsigned short* H  = (unsigned short*)(smem + V_BYTES); // [256][72] bf16
  char* Bsm          = smem + BB_OFF;                     // 2 x 4KB B double-buffer

  const int t    = threadIdx.x;
  const int lane = t & 63;
  const int w    = t >> 6;               // wave: rows [w*64, w*64+64)
  const int l31  = lane & 31, hi = lane >> 5;
  const int b0   = blockIdx.x * 16;

  // ---- stage x: x[b0+bl, i, d] -> Vb[bl*16+d][i] (bf16); cols 39..55 zeroed ----
  const float* xb = X + (size_t)b0 * 624;   // 16*39*16 = 9984 floats
  for (int f = t * 4; f < 9984; f += 1024) {
    float4 v4 = *(const float4*)(xb + f);
    int bl = f / 624;
    int rem = f - bl * 624;
    int i = rem >> 4, d0 = rem & 15;
    int r = bl * 16 + d0;
    Vb[(r + 0) * VS + i] = f2bf(v4.x);
    Vb[(r + 1) * VS + i] = f2bf(v4.y);
    Vb[(r + 2) * VS + i] = f2bf(v4.z);
    Vb[(r + 3) * VS + i] = f2bf(v4.w);
  }
  #pragma unroll
  for (int c = 39; c < VS; c++) Vb[t * VS + c] = 0;

  // stage B slice 0 into buf0
  stage16((const char*)wpk + ((size_t)0 * 256 + w * 64 + lane) * 16, Bsm + (w << 10));
  asm volatile("s_waitcnt vmcnt(0)" ::: "memory");
  __syncthreads();   // V ready + B slice 0 ready

  const int row0 = w * 64 + l31;
  const int row1 = row0 + 32;

  // register-cache packed vj windows (ig-invariant): j0 = 16rr + 8hi
  uint4 vp0[3], vp1[3];
  #pragma unroll
  for (int rr = 0; rr < 3; rr++) {
    vp0[rr] = *(const uint4*)(Vb + row0 * VS + 16 * rr + 8 * hi);
    vp1[rr] = *(const uint4*)(Vb + row1 * VS + 16 * rr + 8 * hi);
  }

  f32x16 acc[2][4];
  #pragma unroll
  for (int mi = 0; mi < 2; mi++)
    #pragma unroll
    for (int nb = 0; nb < 4; nb++)
      #pragma unroll
      for (int e = 0; e < 16; e++) acc[mi][nb][e] = 0.f;

  // ================= layer 0: 40 i-groups x 3 slices =================
  int sg = 0;
  #pragma unroll 1
  for (int ig = 0; ig < 40; ig++) {
    float vi0 = bf2f(Vb[row0 * VS + ig]);
    float vi1 = bf2f(Vb[row1 * VS + ig]);
    #pragma unroll
    for (int rr = 0; rr < 3; rr++) {
      // stage next slice (async; lands during MFMA below)
      stage16((const char*)wpk + ((size_t)(sg + 1) * 256 + w * 64 + lane) * 16,
              Bsm + (((sg + 1) & 1) << 12) + (w << 10));
      const char* bb = Bsm + ((sg & 1) << 12) + (lane << 4);
      short8 bf0 = *(const short8*)(bb + 0);
      short8 bf1 = *(const short8*)(bb + 1024);
      short8 bf2 = *(const short8*)(bb + 2048);
      short8 bf3 = *(const short8*)(bb + 3072);
      short8 a0 = mk_a(vi0, vp0[rr]);
      short8 a1 = mk_a(vi1, vp1[rr]);
      acc[0][0] = __builtin_amdgcn_mfma_f32_32x32x16_bf16(a0, bf0, acc[0][0], 0, 0, 0);
      acc[1][0] = __builtin_amdgcn_mfma_f32_32x32x16_bf16(a1, bf0, acc[1][0], 0, 0, 0);
      acc[0][1] = __builtin_amdgcn_mfma_f32_32x32x16_bf16(a0, bf1, acc[0][1], 0, 0, 0);
      acc[1][1] = __builtin_amdgcn_mfma_f32_32x32x16_bf16(a1, bf1, acc[1][1], 0, 0, 0);
      acc[0][2] = __builtin_amdgcn_mfma_f32_32x32x16_bf16(a0, bf2, acc[0][2], 0, 0, 0);
      acc[1][2] = __builtin_amdgcn_mfma_f32_32x32x16_bf16(a1, bf2, acc[1][2], 0, 0, 0);
      acc[0][3] = __builtin_amdgcn_mfma_f32_32x32x16_bf16(a0, bf3, acc[0][3], 0, 0, 0);
      acc[1][3] = __builtin_amdgcn_mfma_f32_32x32x16_bf16(a1, bf3, acc[1][3], 0, 0, 0);
      asm volatile("s_waitcnt vmcnt(0)" ::: "memory");
      __syncthreads();
      sg++;
    }
  }

  // ---- layer-0 epilogue ----
  // C/D layout (HW-verified): col = lane&31, rowtile = (r&3) + 8*(r>>2) + 4*hi.
  #pragma unroll
  for (int mi = 0; mi < 2; mi++)
    #pragma unroll
    for (int nb = 0; nb < 2; nb++)
      #pragma unroll
      for (int r = 0; r < 16; r++) {
        int rt = (r & 3) + 8 * (r >> 2) + 4 * hi;
        H[(w * 64 + mi * 32 + rt) * HS + nb * 32 + l31] = f2bf(fmaxf(acc[mi][nb][r], 0.f));
      }
  #pragma unroll
  for (int mi = 0; mi < 2; mi++)
    #pragma unroll
    for (int nb = 2; nb < 4; nb++) {
      float s0 = 0.f, s1 = 0.f;
      #pragma unroll
      for (int r = 0; r < 8; r++)  s0 += fmaxf(acc[mi][nb][r], 0.f);   // rows  0..15
      #pragma unroll
      for (int r = 8; r < 16; r++) s1 += fmaxf(acc[mi][nb][r], 0.f);   // rows 16..31
      s0 += __shfl_xor(s0, 32);
      s1 += __shfl_xor(s1, 32);
      out[(size_t)(b0 + 4 * w + 2 * mi + hi) * 192 + (nb - 2) * 32 + l31] = hi ? s1 : s0;
    }
  __syncthreads();   // H ready

  // register-cache packed hj windows: j0 = 16rr + 8hi (H read-only hereafter)
  uint4 hp0[4], hp1[4];
  #pragma unroll
  for (int rr = 0; rr < 4; rr++) {
    hp0[rr] = *(const uint4*)(H + row0 * HS + 16 * rr + 8 * hi);
    hp1[rr] = *(const uint4*)(H + row1 * HS + 16 * rr + 8 * hi);
  }

  #pragma unroll
  for (int mi = 0; mi < 2; mi++)
    #pragma unroll
    for (int nb = 0; nb < 4; nb++)
      #pragma unroll
      for (int e = 0; e < 16; e++) acc[mi][nb][e] = 0.f;

  // ================= layer 1: 39 i-groups x 4 slices =================
  #pragma unroll 1
  for (int ig = 0; ig < 39; ig++) {
    float vi0 = bf2f(Vb[row0 * VS + ig]);
    float vi1 = bf2f(Vb[row1 * VS + ig]);
    #pragma unroll
    for (int rr = 0; rr < 4; rr++) {
      if (sg + 1 < NSL)
        stage16((const char*)wpk + ((size_t)(sg + 1) * 256 + w * 64 + lane) * 16,
                Bsm + (((sg + 1) & 1) << 12) + (w << 10));
      const char* bb = Bsm + ((sg & 1) << 12) + (lane << 4);
      short8 bf0 = *(const short8*)(bb + 0);
      short8 bf1 = *(const short8*)(bb + 1024);
      short8 bf2 = *(const short8*)(bb + 2048);
      short8 bf3 = *(const short8*)(bb + 3072);
      short8 a0 = mk_a(vi0, hp0[rr]);
      short8 a1 = mk_a(vi1, hp1[rr]);
      acc[0][0] = __builtin_amdgcn_mfma_f32_32x32x16_bf16(a0, bf0, acc[0][0], 0, 0, 0);
      acc[1][0] = __builtin_amdgcn_mfma_f32_32x32x16_bf16(a1, bf0, acc[1][0], 0, 0, 0);
      acc[0][1] = __builtin_amdgcn_mfma_f32_32x32x16_bf16(a0, bf1, acc[0][1], 0, 0, 0);
      acc[1][1] = __builtin_amdgcn_mfma_f32_32x32x16_bf16(a1, bf1, acc[1][1], 0, 0, 0);
      acc[0][2] = __builtin_amdgcn_mfma_f32_32x32x16_bf16(a0, bf2, acc[0][2], 0, 0, 0);
      acc[1][2] = __builtin_amdgcn_mfma_f32_32x32x16_bf16(a1, bf2, acc[1][2], 0, 0, 0);
      acc[0][3] = __builtin_amdgcn_mfma_f32_32x32x16_bf16(a0, bf3, acc[0][3], 0, 0, 0);
      acc[1][3] = __builtin_amdgcn_mfma_f32_32x32x16_bf16(a1, bf3, acc[1][3], 0, 0, 0);
      asm volatile("s_waitcnt vmcnt(0)" ::: "memory");
      __syncthreads();
      sg++;
    }
  }

  // ---- layer-1 epilogue: relu, sum over d, out[b, 64:192] ----
  #pragma unroll
  for (int mi = 0; mi < 2; mi++)
    #pragma unroll
    for (int nb = 0; nb < 4; nb++) {
      float s0 = 0.f, s1 = 0.f;
      #pragma unroll
      for (int r = 0; r < 8; r++)  s0 += fmaxf(acc[mi][nb][r], 0.f);
      #pragma unroll
      for (int r = 8; r < 16; r++) s1 += fmaxf(acc[mi][nb][r], 0.f);
      s0 += __shfl_xor(s0, 32);
      s1 += __shfl_xor(s1, 32);
      out[(size_t)(b0 + 4 * w + 2 * mi + hi) * 192 + 64 + nb * 32 + l31] = hi ? s1 : s0;
    }
}

extern "C" void kernel_launch(void* const* d_in, const int* in_sizes, int n_in,
                              void* d_out, int out_size, void* d_ws, size_t ws_size,
                              hipStream_t stream) {
  (void)in_sizes; (void)n_in; (void)out_size; (void)ws_size;
  const float* X  = (const float*)d_in[0];   // [8192,39,16]
  const float* W0 = (const float*)d_in[1];   // [1521,128]
  const float* W1 = (const float*)d_in[2];   // [2496,128]
  float* out = (float*)d_out;                // [8192,192]
  short8* wpk = (short8*)d_ws;               // packed bf16 W0|W1, 1.13 MB

  // dynamic LDS 73728 B > 64KB: raise the limit (host-side API, graph-safe)
  (void)hipFuncSetAttribute((const void*)cin_main,
                            hipFuncAttributeMaxDynamicSharedMemorySize, SMEM_BYTES);

  pack_w<<<(NFRAG + 255) / 256, 256, 0, stream>>>(W0, W1, wpk);
  cin_main<<<512, 256, SMEM_BYTES, stream>>>(X, wpk, out);
}